// Round 11
// baseline (303.122 us; speedup 1.0000x reference)
//
#include <hip/hip_runtime.h>
#include <math.h>

// Problem constants: N=200 LSTMs, B=100, T=256, D=5 (io), H=20 (units)
constexpr int NL = 200;
constexpr int B  = 100;
constexpr int T  = 256;
constexpr int D  = 5;
constexpr int H  = 20;
constexpr int NW = 7;       // 16-batch groups per LSTM; 7*16=112 >= 100
constexpr int KPH = 24;     // LDS row pitch in shorts (48 B) — h region only
constexpr int NWAVE = 5;    // wave m computes recurrence tile Mt=m
constexpr int BLKT  = 64 * NWAVE;     // 320 threads
constexpr int BUFB  = 16 * KPH * 2;   // 768 B per buffer

// k-axis layout of the per-batch data column (K=32):
//   k 0..23  = h region in LDS, k = g*6 + mt  (hh = mt*4 + g; mt==5 -> 0)
//   k 24..28 = x_t[0..4]  — supplied from REGISTERS by lanes g4==3 (xpack)
//   k 30     = 1.0 (bias slot, static in xpack), k 29,31 = 0

typedef float  f32x4  __attribute__((ext_vector_type(4)));
typedef short  bf16x8 __attribute__((ext_vector_type(8)));

__device__ __forceinline__ float rcpf(float x) { return __builtin_amdgcn_rcpf(x); }

#if __has_builtin(__builtin_amdgcn_exp2f)
__device__ __forceinline__ float exp2fast(float x) { return __builtin_amdgcn_exp2f(x); }
#else
__device__ __forceinline__ float exp2fast(float x) { return __expf(x * 0.6931471805599453f); }
#endif

// fp32 -> bf16 bits, round-to-nearest-even
__device__ __forceinline__ unsigned short f2bf(float f) {
    union { float f; unsigned u; } v; v.f = f;
    unsigned r = v.u + 0x7fffu + ((v.u >> 16) & 1u);
    return (unsigned short)(r >> 16);
}
__device__ __forceinline__ unsigned pk2bf(float lo, float hi) {
    return (unsigned)f2bf(lo) | ((unsigned)f2bf(hi) << 16);
}

// LDS-only block barrier (global stores / x prefetch stay in flight)
__device__ __forceinline__ void block_sync_lds() {
    asm volatile("s_waitcnt lgkmcnt(0)" ::: "memory");
    __builtin_amdgcn_s_barrier();
}

constexpr float NLOG2E = -1.4426950408889634f;
constexpr float TLOG2E = 2.8853900817779268f;   // 2*log2(e)

__global__ __launch_bounds__(256) void init_out_kernel(const float* __restrict__ dense_b,
                                                       float* __restrict__ out, int n) {
    int i = blockIdx.x * 256 + threadIdx.x;
    if (i < n) out[i] = dense_b[i % D];
}

// Pre-pack x into the register B-fragment layout for k=24..31:
// xpack[b*T+t] = {pk(x0,x1), pk(x2,x3), pk(x4,0), pk(1.0,0)} as bf16 pairs.
__global__ __launch_bounds__(256) void xpack_kernel(const float* __restrict__ x,
                                                    int4* __restrict__ xp) {
    int i = blockIdx.x * 256 + threadIdx.x;   // i = b*T + t
    if (i >= B * T) return;
    const float* s = x + (size_t)i * D;
    int4 v;
    v.x = pk2bf(s[0], s[1]);
    v.y = pk2bf(s[2], s[3]);
    v.z = pk2bf(s[4], 0.0f);
    v.w = 0x00003F80;                         // (bf16 1.0, 0)
    xp[i] = v;
}

// One block per (lstm n, 16-batch group w); 5 UNIFORM waves per block.
// Every wave, every step: 1 ds_read_b128 (h region; g4==3 lanes substitute the
// register x-fragment) -> recurrence MFMA (tile Mt=wid) + dense MFMA
// (duplicated; wave wid stores only slice d==wid) -> activation chain ->
// 1 ds_write_b16 (h). No special-role waves -> no barrier stragglers.
template<bool USE_WS>
__global__ __attribute__((amdgpu_flat_work_group_size(BLKT, BLKT)))
void lstm5u_kernel(
    const int4*  __restrict__ xp,   // [B][T] packed x fragments
    const float* __restrict__ Wg,   // [N][D][4H]
    const float* __restrict__ Ug,   // [N][H][4H]
    const float* __restrict__ bg,   // [N][4H]
    const float* __restrict__ dWg,  // [N*H][D]
    float* __restrict__ pw,         // [N][T][D][B] partials (USE_WS)
    float* __restrict__ out)        // [B][T][D] (atomic fallback)
{
    const int blk = blockIdx.x;            // 0..1399
    const int n   = blk / NW;
    const int w   = blk % NW;
    const int tid = threadIdx.x;
    const int wid = tid >> 6;              // 0..4 = Mt of this wave
    const int l   = tid & 63;
    const int c16 = l & 15;
    const int g4  = l >> 4;

    __shared__ __align__(16) short bcol[2][16][KPH];   // double-buffered h

    for (int i = tid; i < 2 * 16 * KPH / 2; i += BLKT)
        ((int*)&bcol[0][0][0])[i] = 0;

    const float* Un = Ug  + (size_t)n * H * 4 * H;
    const float* Wn = Wg  + (size_t)n * D * 4 * H;
    const float* bn = bg  + (size_t)n * 4 * H;
    const float* dn = dWg + (size_t)n * H * D;

    // ---- recurrence A fragment (Mt = wid), k = 8*g4 + j ----
    const int gateA = c16 & 3;
    const int hA4   = c16 >> 2;
    const float sA  = (gateA == 2) ? TLOG2E : NLOG2E;
    const int colA  = gateA * H + (wid * 4 + hA4);
    bf16x8 afrag;
    #pragma unroll
    for (int j = 0; j < 8; ++j) {
        const int k = 8 * g4 + j;
        float v = 0.0f;
        if (k < 24) {                          // h region: k = g*6 + mt
            const int mt = k % 6, gg = k / 6;
            if (mt < 5) v = Un[(mt * 4 + gg) * 4 * H + colA];
        } else if (k < 24 + D) {               // x region
            v = Wn[(k - 24) * 4 * H + colA];
        } else if (k == 30) {                  // bias slot
            v = bn[colA];
        }
        afrag[j] = (short)f2bf(sA * v);
    }
    // ---- dense A fragment (ALL waves): rows c16<5 = d, h region only ----
    bf16x8 afd;
    #pragma unroll
    for (int j = 0; j < 8; ++j) {
        const int k = 8 * g4 + j;
        float v = 0.0f;
        if (c16 < D && k < 24) {
            const int mt = k % 6, gg = k / 6;
            if (mt < 5) v = dn[(mt * 4 + gg) * D + c16];
        }
        afd[j] = (short)f2bf(v);
    }

    const int  bgl    = w * 16 + c16;
    const bool bvalid = bgl < B;
    const int4* xq = xp + (size_t)(bvalid ? bgl : 0) * T;

    // dense store role: wave wid stores d = wid from lanes g4 == wid>>2, reg = wid&3
    const bool dlane = bvalid && (g4 == (wid >> 2));
    const int  dreg  = wid & 3;
    float* pd = USE_WS ? (pw + (size_t)n * T * (D * B) + wid * B + bgl)
                       : (out + ((size_t)bgl * T) * D + wid);

    char* lb = (char*)&bcol[0][0][0];
    const int rdoff = c16 * 48 + (g4 < 3 ? g4 * 16 : 32);   // g4==3 clamped (discarded)
    const int woff  = c16 * 48 + (g4 * 6 + wid) * 2;

    __syncthreads();                          // zero-init visible

    int4 xf = xq[0];                          // x(0) fragment
    float cst = 0.0f;
    const f32x4 z4 = {0.0f, 0.0f, 0.0f, 0.0f};

    auto step = [&](const int p, const int t) {
        // B fragment: h from LDS (g4<3) or register x fragment (g4==3)
        const int4 hvi = *(const int4*)(lb + p * BUFB + rdoff);
        int4 bi;
        bi.x = (g4 == 3) ? xf.x : hvi.x;
        bi.y = (g4 == 3) ? xf.y : hvi.y;
        bi.z = (g4 == 3) ? xf.z : hvi.z;
        bi.w = (g4 == 3) ? xf.w : hvi.w;
        union { int4 i; bf16x8 h; } u; u.i = bi;
        const bf16x8 bfrag = u.h;

        // prefetch x(t+1) — consumed next step
        xf = xq[(t + 1 < T) ? t + 1 : T - 1];

        // dense for step t-1 (h(t-1) is in bfrag; x rows of afd are zero)
        const f32x4 accd = __builtin_amdgcn_mfma_f32_16x16x32_bf16(afd, bfrag, z4, 0, 0, 0);
        if (t > 0 && dlane) {
            if (USE_WS) pd[(size_t)(t - 1) * (D * B)] = accd[dreg];
            else        atomicAdd(&pd[(size_t)(t - 1) * D], accd[dreg]);
        }

        // recurrence tile Mt = wid
        const f32x4 acc = __builtin_amdgcn_mfma_f32_16x16x32_bf16(afrag, bfrag, z4, 0, 0, 0);
        // acc = {-z_i, -z_f, 2*z_g, -z_o} * log2e  (bias via k=30)
        const float iv = rcpf(1.0f + exp2fast(acc[0]));
        const float fv = rcpf(1.0f + exp2fast(acc[1]));
        const float gv = fmaf(-2.0f, rcpf(exp2fast(acc[2]) + 1.0f), 1.0f);
        const float ov = rcpf(1.0f + exp2fast(acc[3]));
        cst = fmaf(fv, cst, iv * gv);
        const float th = fmaf(-2.0f, rcpf(exp2fast(TLOG2E * cst) + 1.0f), 1.0f);
        const float hv = ov * th;

        unsigned hp;
        asm("v_cvt_pk_bf16_f32 %0, %1, %2" : "=v"(hp) : "v"(hv), "v"(hv));
        *(short*)(lb + (p ^ 1) * BUFB + woff) = (short)hp;

        block_sync_lds();
    };

    for (int t = 0; t < T; t += 2) { step(0, t); step(1, t + 1); }

    // final dense: h(T-1) sits in buffer 0
    {
        const int4 hvi = *(const int4*)(lb + rdoff);
        union { int4 i; bf16x8 h; } u; u.i = hvi;   // g4==3 rows of afd are zero
        const f32x4 accd = __builtin_amdgcn_mfma_f32_16x16x32_bf16(afd, u.h, z4, 0, 0, 0);
        if (dlane) {
            if (USE_WS) pd[(size_t)(T - 1) * (D * B)] = accd[dreg];
            else        atomicAdd(&pd[(size_t)(T - 1) * D], accd[dreg]);
        }
    }
}

// out[b][t][d] = dense_b[d] + sum_n pw[n][t][d][b]  (coalesced reads)
__global__ __launch_bounds__(512) void reduce_kernel(
    const float* __restrict__ pw, const float* __restrict__ dense_b,
    float* __restrict__ out)
{
    const int t    = blockIdx.x;
    const int flat = threadIdx.x;              // d*B + b, 0..499
    if (flat >= B * D) return;
    const int d = flat / B;
    const int b = flat % B;
    const float* p = pw + (size_t)t * (D * B) + flat;
    constexpr size_t stride = (size_t)T * D * B;
    float a0 = 0.0f, a1 = 0.0f;
    #pragma unroll 10
    for (int n = 0; n < NL; n += 2) {
        a0 += p[(size_t)n * stride];
        a1 += p[(size_t)(n + 1) * stride];
    }
    out[((size_t)b * T + t) * D + d] = a0 + a1 + dense_b[d];
}

extern "C" void kernel_launch(void* const* d_in, const int* in_sizes, int n_in,
                              void* d_out, int out_size, void* d_ws, size_t ws_size,
                              hipStream_t stream) {
    const float* x   = (const float*)d_in[0];
    const float* Wg  = (const float*)d_in[1];
    const float* Ug  = (const float*)d_in[2];
    const float* bg  = (const float*)d_in[3];
    const float* dWg = (const float*)d_in[4];
    const float* dbv = (const float*)d_in[5];
    float* out = (float*)d_out;

    const size_t xpk_bytes = (size_t)B * T * sizeof(int4);        // 409,600 (256-aligned)
    const size_t pw_bytes  = (size_t)NL * T * D * B * sizeof(float);  // 102.4 MB

    int4* xpk = (int4*)d_ws;
    xpack_kernel<<<(B * T + 255) / 256, 256, 0, stream>>>(x, xpk);

    if (ws_size >= xpk_bytes + pw_bytes) {
        float* pw = (float*)((char*)d_ws + xpk_bytes);
        lstm5u_kernel<true><<<NL * NW, BLKT, 0, stream>>>(xpk, Wg, Ug, bg, dWg, pw, out);
        reduce_kernel<<<T, 512, 0, stream>>>(pw, dbv, out);
    } else {
        init_out_kernel<<<(out_size + 255) / 256, 256, 0, stream>>>(dbv, out, out_size);
        lstm5u_kernel<false><<<NL * NW, BLKT, 0, stream>>>(xpk, Wg, Ug, bg, dWg, nullptr, out);
    }
}

// Round 12
// 251.701 us; speedup vs baseline: 1.2043x; 1.2043x over previous
//
#include <hip/hip_runtime.h>
#include <math.h>

// Problem constants: N=200 LSTMs, B=100, T=256, D=5 (io), H=20 (units)
constexpr int NL = 200;
constexpr int B  = 100;
constexpr int T  = 256;
constexpr int D  = 5;
constexpr int H  = 20;
constexpr int NW   = 7;      // 16-batch groups per LSTM; 7*16=112 >= 100
constexpr int BPAD = 112;    // padded batch dim of xe (zeros for b>=100)

// K=32 bijection (A and B share it positionally, so any bijection is valid):
//   k = 8*g4 + j ; j in 0..4  -> hh = 4*j + g4   (lane-local recurrence!)
//   g4=0: j5,j6,j7 = x0,x1,x2 ; g4=1: j5,j6 = x3,x4, j7 = bias(1.0)
//   g4=2,3: j>=5 -> 0
// Lane (g4,c16) C-output rows 4*g4+reg give gates of hh=4*Mt+g4 -> the SAME
// lane owns exactly the hh values (hh mod 4 == g4) its next-step B-fragment
// needs: the h state never leaves the lane's registers.

typedef float  f32x4  __attribute__((ext_vector_type(4)));
typedef short  bf16x8 __attribute__((ext_vector_type(8)));

__device__ __forceinline__ float rcpf(float x) { return __builtin_amdgcn_rcpf(x); }

#if __has_builtin(__builtin_amdgcn_exp2f)
__device__ __forceinline__ float exp2fast(float x) { return __builtin_amdgcn_exp2f(x); }
#else
__device__ __forceinline__ float exp2fast(float x) { return __expf(x * 0.6931471805599453f); }
#endif

// fp32 -> bf16 bits, round-to-nearest-even
__device__ __forceinline__ unsigned short f2bf(float f) {
    union { float f; unsigned u; } v; v.f = f;
    unsigned r = v.u + 0x7fffu + ((v.u >> 16) & 1u);
    return (unsigned short)(r >> 16);
}
__device__ __forceinline__ unsigned pk2bf(float lo, float hi) {
    return (unsigned)f2bf(lo) | ((unsigned)f2bf(hi) << 16);
}

constexpr float NLOG2E = -1.4426950408889634f;
constexpr float TLOG2E = 2.8853900817779268f;   // 2*log2(e)

__global__ __launch_bounds__(256) void init_out_kernel(const float* __restrict__ dense_b,
                                                       float* __restrict__ out, int n) {
    int i = blockIdx.x * 256 + threadIdx.x;
    if (i < n) out[i] = dense_b[i % D];
}

// xe[g][t][b] (g=0,1): per-lane x/bias fragment pieces, [t][b] order so a
// wave's 16 consecutive b lanes read one 128B line per g.
//   g=0: {bf16(x0)<<16, pk(x1,x2)}   g=1: {bf16(x3)<<16, pk(x4,1.0)}
__global__ __launch_bounds__(256) void xpack_kernel(const float* __restrict__ x,
                                                    int2* __restrict__ xe) {
    int i = blockIdx.x * 256 + threadIdx.x;
    if (i >= 2 * T * BPAD) return;
    const int g = i / (T * BPAD);
    const int r = i % (T * BPAD);
    const int t = r / BPAD;
    const int b = r % BPAD;
    int2 v = {0, 0};
    if (b < B) {
        const float* s = x + ((size_t)b * T + t) * D;
        if (g == 0) { v.x = (int)((unsigned)f2bf(s[0]) << 16); v.y = (int)pk2bf(s[1], s[2]); }
        else        { v.x = (int)((unsigned)f2bf(s[3]) << 16); v.y = (int)pk2bf(s[4], 1.0f); }
    }
    xe[i] = v;
}

__device__ __forceinline__ float lstm_act(const f32x4 a, float& c) {
    // a = {-z_i, -z_f, 2*z_g, -z_o} * log2e (bias folded into MFMA A)
    const float iv = rcpf(1.0f + exp2fast(a[0]));
    const float fv = rcpf(1.0f + exp2fast(a[1]));
    const float gv = fmaf(-2.0f, rcpf(exp2fast(a[2]) + 1.0f), 1.0f);
    const float ov = rcpf(1.0f + exp2fast(a[3]));
    c = fmaf(fv, c, iv * gv);
    const float th = fmaf(-2.0f, rcpf(exp2fast(TLOG2E * c) + 1.0f), 1.0f);
    return ov * th;
}

// ONE 64-thread wave per (lstm n, 16-batch group w). Entire recurrence in
// registers: no LDS, no barriers, no cross-lane ops. Per step: pack bfrag
// (3 cvt_pk + or), 6 MFMAs (5 gate tiles + 1 dense), 5 activation chains,
// 5 coalesced dense stores (d slices), 1 x-fragment prefetch (2 lines/wave).
template<bool USE_WS>
__global__ __attribute__((amdgpu_flat_work_group_size(64, 64),
                          amdgpu_waves_per_eu(1, 2)))
void lstm_reg_kernel(
    const int2*  __restrict__ xe,   // [2][T][BPAD] packed x pieces
    const float* __restrict__ Wg,   // [N][D][4H]
    const float* __restrict__ Ug,   // [N][H][4H]
    const float* __restrict__ bg,   // [N][4H]
    const float* __restrict__ dWg,  // [N*H][D]
    float* __restrict__ pw,         // [N][T][D][B] partials (USE_WS)
    float* __restrict__ out)        // [B][T][D] (atomic fallback)
{
    const int blk = blockIdx.x;            // 0..1399
    const int n   = blk / NW;
    const int w   = blk % NW;
    const int l   = threadIdx.x;           // 0..63
    const int c16 = l & 15;
    const int g4  = l >> 4;

    const float* Un = Ug  + (size_t)n * H * 4 * H;
    const float* Wn = Wg  + (size_t)n * D * 4 * H;
    const float* bn = bg  + (size_t)n * 4 * H;
    const float* dn = dWg + (size_t)n * H * D;

    // ---- recurrence A fragments (Mt = 0..4), element j <-> k = 8*g4 + j ----
    const int gateA = c16 & 3;
    const int hA4   = c16 >> 2;
    const float sA  = (gateA == 2) ? TLOG2E : NLOG2E;
    bf16x8 af0, af1, af2, af3, af4;
    {
        auto build = [&](int Mt) {
            const int colA = gateA * H + (Mt * 4 + hA4);
            bf16x8 a;
            #pragma unroll
            for (int j = 0; j < 8; ++j) {
                float v = 0.0f;
                if (j < 5) {                         // h rows: hh = 4*j + g4
                    v = Un[(4 * j + g4) * 4 * H + colA];
                } else if (g4 == 0) {                // x rows 0..2
                    v = Wn[(j - 5) * 4 * H + colA];
                } else if (g4 == 1) {                // x rows 3,4 + bias
                    v = (j < 7) ? Wn[(j - 2) * 4 * H + colA] : bn[colA];
                }
                a[j] = (short)f2bf(sA * v);
            }
            return a;
        };
        af0 = build(0); af1 = build(1); af2 = build(2); af3 = build(3); af4 = build(4);
    }
    // ---- dense A fragment: rows c16<5 = d, h rows only ----
    bf16x8 afd;
    #pragma unroll
    for (int j = 0; j < 8; ++j) {
        float v = 0.0f;
        if (c16 < D && j < 5) v = dn[(4 * j + g4) * D + c16];
        afd[j] = (short)f2bf(v);
    }

    const int  bgl    = w * 16 + c16;          // 0..111 (pad cols compute junk, never stored)
    const bool bvalid = bgl < B;
    const int2* xlane = xe + (size_t)(g4 & 1) * T * BPAD + bgl;   // valid for g4<2
    float* pbase = USE_WS ? (pw + (size_t)n * T * (D * B) + bgl)
                          : (out + (size_t)bgl * T * D);

    int2 xfA = {0, 0}, xfB = {0, 0};
    if (g4 < 2) {
        xfA = xlane[0];
        xfB = xlane[BPAD];                     // t = 1
    }

    float h0 = 0.f, h1 = 0.f, h2 = 0.f, h3 = 0.f, h4 = 0.f;
    float c0 = 0.f, c1 = 0.f, c2 = 0.f, c3 = 0.f, c4 = 0.f;
    const f32x4 z4 = {0.f, 0.f, 0.f, 0.f};
    const float fzero = 0.0f;

    auto body = [&](int2& xf, int t) {
        // pack B fragment: [h(t-1) | x(t) | bias]
        unsigned w0, w1, w2;
        asm("v_cvt_pk_bf16_f32 %0, %1, %2" : "=v"(w0) : "v"(h0), "v"(h1));
        asm("v_cvt_pk_bf16_f32 %0, %1, %2" : "=v"(w1) : "v"(h2), "v"(h3));
        asm("v_cvt_pk_bf16_f32 %0, %1, %2" : "=v"(w2) : "v"(h4), "v"(fzero));
        w2 |= (unsigned)xf.x;
        union { int4 i; bf16x8 v; } ub;
        ub.i = make_int4((int)w0, (int)w1, (int)w2, xf.y);
        const bf16x8 bfrag = ub.v;

        // 6 MFMAs
        const f32x4 ad = __builtin_amdgcn_mfma_f32_16x16x32_bf16(afd, bfrag, z4, 0, 0, 0);
        const f32x4 a0 = __builtin_amdgcn_mfma_f32_16x16x32_bf16(af0, bfrag, z4, 0, 0, 0);
        const f32x4 a1 = __builtin_amdgcn_mfma_f32_16x16x32_bf16(af1, bfrag, z4, 0, 0, 0);
        const f32x4 a2 = __builtin_amdgcn_mfma_f32_16x16x32_bf16(af2, bfrag, z4, 0, 0, 0);
        const f32x4 a3 = __builtin_amdgcn_mfma_f32_16x16x32_bf16(af3, bfrag, z4, 0, 0, 0);
        const f32x4 a4 = __builtin_amdgcn_mfma_f32_16x16x32_bf16(af4, bfrag, z4, 0, 0, 0);

        // prefetch x fragment for t+2 (consumed two bodies later)
        if (g4 < 2) {
            const int tc = (t + 2 < T) ? t + 2 : T - 1;
            xf = xlane[(size_t)tc * BPAD];
        }

        // dense result is for step t-1 (bfrag held h(t-1))
        if (t > 0) {
            if (USE_WS) {
                float* pt = pbase + (size_t)(t - 1) * (D * B);
                if (bvalid && g4 == 0) {
                    pt[0 * B] = ad[0]; pt[1 * B] = ad[1];
                    pt[2 * B] = ad[2]; pt[3 * B] = ad[3];
                } else if (bvalid && g4 == 1) {
                    pt[4 * B] = ad[0];
                }
            } else {
                float* pt = pbase + (size_t)(t - 1) * D;
                if (bvalid && g4 == 0) {
                    atomicAdd(&pt[0], ad[0]); atomicAdd(&pt[1], ad[1]);
                    atomicAdd(&pt[2], ad[2]); atomicAdd(&pt[3], ad[3]);
                } else if (bvalid && g4 == 1) {
                    atomicAdd(&pt[4], ad[0]);
                }
            }
        }

        // activations -> h(t), c(t)  (lane-local; feeds next body's pack)
        h0 = lstm_act(a0, c0);
        h1 = lstm_act(a1, c1);
        h2 = lstm_act(a2, c2);
        h3 = lstm_act(a3, c3);
        h4 = lstm_act(a4, c4);
    };

    for (int t = 0; t < T; t += 2) {
        body(xfA, t);
        body(xfB, t + 1);
    }

    // final dense for h(T-1)
    {
        unsigned w0, w1, w2;
        asm("v_cvt_pk_bf16_f32 %0, %1, %2" : "=v"(w0) : "v"(h0), "v"(h1));
        asm("v_cvt_pk_bf16_f32 %0, %1, %2" : "=v"(w1) : "v"(h2), "v"(h3));
        asm("v_cvt_pk_bf16_f32 %0, %1, %2" : "=v"(w2) : "v"(h4), "v"(fzero));
        union { int4 i; bf16x8 v; } ub;
        ub.i = make_int4((int)w0, (int)w1, (int)w2, 0);
        const f32x4 ad = __builtin_amdgcn_mfma_f32_16x16x32_bf16(afd, ub.v, z4, 0, 0, 0);
        if (USE_WS) {
            float* pt = pbase + (size_t)(T - 1) * (D * B);
            if (bvalid && g4 == 0) {
                pt[0 * B] = ad[0]; pt[1 * B] = ad[1];
                pt[2 * B] = ad[2]; pt[3 * B] = ad[3];
            } else if (bvalid && g4 == 1) {
                pt[4 * B] = ad[0];
            }
        } else {
            float* pt = pbase + (size_t)(T - 1) * D;
            if (bvalid && g4 == 0) {
                atomicAdd(&pt[0], ad[0]); atomicAdd(&pt[1], ad[1]);
                atomicAdd(&pt[2], ad[2]); atomicAdd(&pt[3], ad[3]);
            } else if (bvalid && g4 == 1) {
                atomicAdd(&pt[4], ad[0]);
            }
        }
    }
}

// out[b][t][d] = dense_b[d] + sum_n pw[n][t][d][b]  (coalesced reads)
__global__ __launch_bounds__(512) void reduce_kernel(
    const float* __restrict__ pw, const float* __restrict__ dense_b,
    float* __restrict__ out)
{
    const int t    = blockIdx.x;
    const int flat = threadIdx.x;              // d*B + b, 0..499
    if (flat >= B * D) return;
    const int d = flat / B;
    const int b = flat % B;
    const float* p = pw + (size_t)t * (D * B) + flat;
    constexpr size_t stride = (size_t)T * D * B;
    float a0 = 0.0f, a1 = 0.0f;
    #pragma unroll 10
    for (int n = 0; n < NL; n += 2) {
        a0 += p[(size_t)n * stride];
        a1 += p[(size_t)(n + 1) * stride];
    }
    out[((size_t)b * T + t) * D + d] = a0 + a1 + dense_b[d];
}

extern "C" void kernel_launch(void* const* d_in, const int* in_sizes, int n_in,
                              void* d_out, int out_size, void* d_ws, size_t ws_size,
                              hipStream_t stream) {
    const float* x   = (const float*)d_in[0];
    const float* Wg  = (const float*)d_in[1];
    const float* Ug  = (const float*)d_in[2];
    const float* bg  = (const float*)d_in[3];
    const float* dWg = (const float*)d_in[4];
    const float* dbv = (const float*)d_in[5];
    float* out = (float*)d_out;

    const size_t xe_bytes = (size_t)2 * T * BPAD * sizeof(int2);      // 458,752
    const size_t pw_bytes = (size_t)NL * T * D * B * sizeof(float);   // 102.4 MB

    int2* xe = (int2*)d_ws;
    xpack_kernel<<<(2 * T * BPAD + 255) / 256, 256, 0, stream>>>(x, xe);

    if (ws_size >= xe_bytes + pw_bytes) {
        float* pw = (float*)((char*)d_ws + xe_bytes);
        lstm_reg_kernel<true><<<NL * NW, 64, 0, stream>>>(xe, Wg, Ug, bg, dWg, pw, out);
        reduce_kernel<<<T, 512, 0, stream>>>(pw, dbv, out);
    } else {
        init_out_kernel<<<(out_size + 255) / 256, 256, 0, stream>>>(dbv, out, out_size);
        lstm_reg_kernel<false><<<NL * NW, 64, 0, stream>>>(xe, Wg, Ug, bg, dWg, nullptr, out);
    }
}